// Round 14
// baseline (475.862 us; speedup 1.0000x reference)
//
#include <hip/hip_runtime.h>

#define EPSF 1e-8f
#define PROB_PENALTYF 1e-4f
#define REV_SCALEF 0.1f
#define INFBITS 0x7F800000u

// verts grid (rev sources: 8000 ~N(0,1) points). span 11.2 covers +-5.6
#define NV 40
#define LOV (-5.6f)
#define HV 0.28f
#define NV3 (NV*NV*NV)     // 64000
// barycenter grid (fwd sources: 16000 barycenters, sigma~0.577). span 6.6
#define NB 48
#define LOB (-3.3f)
#define HB 0.1375f
#define NB3 (NB*NB*NB)     // 110592

#define QBLK 256

__device__ __forceinline__ int cellc(float x, float lo, float invh, int n) {
    int c = (int)floorf((x - lo) * invh);
    return min(max(c, 0), n - 1);
}

// ---------------- kernel 0: zero counts + acc ----------------
__global__ void zero_kernel(unsigned* __restrict__ countsV,
                            unsigned* __restrict__ countsB,
                            float* __restrict__ acc) {
    int i = blockIdx.x * blockDim.x + threadIdx.x;
    if (i < NV3) countsV[i] = 0u;
    if (i < NB3) countsB[i] = 0u;
    if (i < 8)   acc[i] = 0.0f;
}

// ---------------- kernel 1: count (+ materialize orig barycenters) ----------------
__global__ void count_kernel(const float* __restrict__ overts,
                             const int* __restrict__ ofaces,
                             float4* __restrict__ obc4,
                             unsigned* __restrict__ countsV,
                             unsigned* __restrict__ countsB,
                             int n_orig, int f_orig) {
    int i = blockIdx.x * blockDim.x + threadIdx.x;
    const float third = 1.0f / 3.0f;
    if (i < n_orig) {
        float x = overts[3*i], y = overts[3*i+1], z = overts[3*i+2];
        int cx = cellc(x, LOV, 1.0f/HV, NV);
        int cy = cellc(y, LOV, 1.0f/HV, NV);
        int cz = cellc(z, LOV, 1.0f/HV, NV);
        atomicAdd(&countsV[(cz*NV + cy)*NV + cx], 1u);
    }
    if (i < f_orig) {
        int a = ofaces[3*i], b = ofaces[3*i+1], c = ofaces[3*i+2];
        float x = (overts[3*a] + overts[3*b] + overts[3*c]) * third;
        float y = (overts[3*a+1] + overts[3*b+1] + overts[3*c+1]) * third;
        float z = (overts[3*a+2] + overts[3*b+2] + overts[3*c+2]) * third;
        obc4[i] = make_float4(x, y, z, 0.f);
        int cx = cellc(x, LOB, 1.0f/HB, NB);
        int cy = cellc(y, LOB, 1.0f/HB, NB);
        int cz = cellc(z, LOB, 1.0f/HB, NB);
        atomicAdd(&countsB[(cz*NB + cy)*NB + cx], 1u);
    }
}

// ---------------- kernel 2: exclusive scan (block 0: V, block 1: B) ----------------
__global__ void __launch_bounds__(1024)
scan_kernel(const unsigned* __restrict__ countsV, unsigned* __restrict__ startsV,
            unsigned* __restrict__ cursorV,
            const unsigned* __restrict__ countsB, unsigned* __restrict__ startsB,
            unsigned* __restrict__ cursorB) {
    __shared__ unsigned part[1024];
    const unsigned* counts;
    unsigned *starts, *cursor;
    int n;
    if (blockIdx.x == 0) { counts = countsV; starts = startsV; cursor = cursorV; n = NV3; }
    else                 { counts = countsB; starts = startsB; cursor = cursorB; n = NB3; }
    int t = (int)threadIdx.x;
    int C = (n + 1023) >> 10;
    int lo = t * C, hi = min(lo + C, n);
    unsigned s = 0;
    for (int i = lo; i < hi; ++i) s += counts[i];
    part[t] = s;
    __syncthreads();
    for (int off = 1; off < 1024; off <<= 1) {
        unsigned v = part[t];
        unsigned add = (t >= off) ? part[t - off] : 0u;
        __syncthreads();
        part[t] = v + add;
        __syncthreads();
    }
    unsigned base = (t == 0) ? 0u : part[t - 1];
    for (int i = lo; i < hi; ++i) {
        starts[i] = base;
        cursor[i] = base;
        base += counts[i];
    }
}

// ---------------- kernel 3: scatter into sorted arrays ----------------
__global__ void scatter_kernel(const float* __restrict__ overts,
                               const float4* __restrict__ obc4,
                               unsigned* __restrict__ cursorV,
                               unsigned* __restrict__ cursorB,
                               float4* __restrict__ sortedV,
                               float4* __restrict__ sortedB,
                               int n_orig, int f_orig) {
    int i = blockIdx.x * blockDim.x + threadIdx.x;
    if (i < n_orig) {
        float x = overts[3*i], y = overts[3*i+1], z = overts[3*i+2];
        int cx = cellc(x, LOV, 1.0f/HV, NV);
        int cy = cellc(y, LOV, 1.0f/HV, NV);
        int cz = cellc(z, LOV, 1.0f/HV, NV);
        unsigned pos = atomicAdd(&cursorV[(cz*NV + cy)*NV + cx], 1u);
        sortedV[pos] = make_float4(x, y, z, 0.f);
    }
    if (i < f_orig) {
        float4 v = obc4[i];
        int cx = cellc(v.x, LOB, 1.0f/HB, NB);
        int cy = cellc(v.y, LOB, 1.0f/HB, NB);
        int cz = cellc(v.z, LOB, 1.0f/HB, NB);
        unsigned pos = atomicAdd(&cursorB[(cz*NB + cy)*NB + cx], 1u);
        sortedB[pos] = make_float4(v.x, v.y, v.z, 0.f);
    }
}

// ---------------- kernel 4: queries (grid 1-NN) + fused reduction/finalize ----------------
// threads [0,npts): reverse samples vs vert grid; [npts,npts+fs): fwd barycenters
// vs barycenter grid. Exact NN: scan 3^3 cube, then expanding Chebyshev shells;
// stop when best <= (r*H)^2 (points in cells with index-dist >= r+1 are >= r*H
// away, valid with clamped cells both for queries and stored points).
__global__ void __launch_bounds__(QBLK)
query_kernel(const float* __restrict__ sverts, const int* __restrict__ sfaces,
             const float* __restrict__ u1, const float* __restrict__ u2,
             const float* __restrict__ fp,
             const float4* __restrict__ sortedV, const unsigned* __restrict__ startsV,
             const unsigned* __restrict__ countsV,
             const float4* __restrict__ sortedB, const unsigned* __restrict__ startsB,
             const unsigned* __restrict__ countsB,
             float* __restrict__ acc, float* __restrict__ out,
             int fs, int S, int npts, int nq, int nblocks) {
    __shared__ float s1[QBLK], s2[QBLK], s3[QBLK];
    int t = blockIdx.x * blockDim.x + threadIdx.x;
    float fsum = 0.f, rsum = 0.f, rmx = 0.f;
    if (t < nq) {
        bool isRev = (t < npts);
        const float third = 1.0f / 3.0f;
        float qx, qy, qz;
        if (isRev) {
            int f = t / S;
            float rr = sqrtf(u1[t]);
            float uu = u2[t];
            float wa = 1.0f - rr, wb = rr * (1.0f - uu), wc = rr * uu;
            int a = sfaces[3*f], b = sfaces[3*f+1], c = sfaces[3*f+2];
            qx = wa * sverts[3*a] + wb * sverts[3*b] + wc * sverts[3*c];
            qy = wa * sverts[3*a+1] + wb * sverts[3*b+1] + wc * sverts[3*c+1];
            qz = wa * sverts[3*a+2] + wb * sverts[3*b+2] + wc * sverts[3*c+2];
        } else {
            int k = t - npts;
            int a = sfaces[3*k], b = sfaces[3*k+1], c = sfaces[3*k+2];
            qx = (sverts[3*a] + sverts[3*b] + sverts[3*c]) * third;
            qy = (sverts[3*a+1] + sverts[3*b+1] + sverts[3*c+1]) * third;
            qz = (sverts[3*a+2] + sverts[3*b+2] + sverts[3*c+2]) * third;
        }
        const float4* pts = isRev ? sortedV : sortedB;
        const unsigned* starts = isRev ? startsV : startsB;
        const unsigned* counts = isRev ? countsV : countsB;
        float lo = isRev ? LOV : LOB;
        float h  = isRev ? HV  : HB;
        int   n  = isRev ? NV  : NB;
        float invh = 1.0f / h;
        int cx = cellc(qx, lo, invh, n);
        int cy = cellc(qy, lo, invh, n);
        int cz = cellc(qz, lo, invh, n);
        float best = __uint_as_float(INFBITS);

        // ---- cube r<=1 ----
        int x0 = max(cx-1, 0), x1 = min(cx+1, n-1);
        int y0 = max(cy-1, 0), y1 = min(cy+1, n-1);
        int z0 = max(cz-1, 0), z1 = min(cz+1, n-1);
        for (int z = z0; z <= z1; ++z)
            for (int y = y0; y <= y1; ++y)
                for (int x = x0; x <= x1; ++x) {
                    int cid = (z*n + y)*n + x;
                    unsigned sb = starts[cid];
                    unsigned e = sb + counts[cid];
                    for (unsigned i = sb; i < e; ++i) {
                        float4 v = pts[i];
                        float dx = qx - v.x, dy = qy - v.y, dz = qz - v.z;
                        float d2 = fmaf(dx, dx, fmaf(dy, dy, dz * dz));
                        best = fminf(best, d2);
                    }
                }

        // ---- expanding shells (rare path) ----
        int rmaxq = max(max(cx, n-1-cx), max(max(cy, n-1-cy), max(cz, n-1-cz)));
        int r = 1;
        while (best > ((float)r * h) * ((float)r * h) && r < rmaxq) {
            ++r;
            for (int dz = -r; dz <= r; ++dz) {
                int z = cz + dz;
                if (z < 0 || z >= n) continue;
                bool zf = (dz == -r) || (dz == r);
                for (int dy = -r; dy <= r; ++dy) {
                    int y = cy + dy;
                    if (y < 0 || y >= n) continue;
                    bool yf = (dy == -r) || (dy == r);
                    int step = (zf || yf) ? 1 : 2 * r;
                    for (int dx = -r; dx <= r; dx += step) {
                        int x = cx + dx;
                        if (x < 0 || x >= n) continue;
                        int cid = (z*n + y)*n + x;
                        unsigned sb = starts[cid];
                        unsigned e = sb + counts[cid];
                        for (unsigned i = sb; i < e; ++i) {
                            float4 v = pts[i];
                            float ddx = qx - v.x, ddy = qy - v.y, ddz = qz - v.z;
                            float d2 = fmaf(ddx, ddx, fmaf(ddy, ddy, ddz * ddz));
                            best = fminf(best, d2);
                        }
                    }
                }
            }
        }

        if (isRev) {
            float p = fp[t / S];
            rsum = p * best;
            rmx = best;
        } else {
            float p = fp[t - npts];
            fsum = p * best + PROB_PENALTYF * (1.0f - p);
        }
    }

    // ---- block reduction + ticketed finalize ----
    s1[threadIdx.x] = fsum;
    s2[threadIdx.x] = rsum;
    s3[threadIdx.x] = rmx;
    __syncthreads();
    for (int off = QBLK / 2; off > 0; off >>= 1) {
        if ((int)threadIdx.x < off) {
            s1[threadIdx.x] += s1[threadIdx.x + off];
            s2[threadIdx.x] += s2[threadIdx.x + off];
            s3[threadIdx.x] = fmaxf(s3[threadIdx.x], s3[threadIdx.x + off]);
        }
        __syncthreads();
    }
    if (threadIdx.x == 0) {
        atomicAdd(&acc[0], s1[0]);
        atomicAdd(&acc[1], s2[0]);
        atomicMax((unsigned*)&acc[2], __float_as_uint(s3[0]));
        __threadfence();
        unsigned ticket = atomicAdd((unsigned*)&acc[3], 1u);
        if (ticket == (unsigned)(nblocks - 1)) {
            __threadfence();
            float a0 = atomicAdd(&acc[0], 0.0f);
            float a1 = atomicAdd(&acc[1], 0.0f);
            unsigned mb = atomicOr((unsigned*)&acc[2], 0u);
            out[0] = a0 + a1 * (REV_SCALEF / (__uint_as_float(mb) + EPSF));
        }
    }
}

extern "C" void kernel_launch(void* const* d_in, const int* in_sizes, int n_in,
                              void* d_out, int out_size, void* d_ws, size_t ws_size,
                              hipStream_t stream) {
    const float* overts = (const float*)d_in[0];
    const int*   ofaces = (const int*)d_in[1];
    const float* sverts = (const float*)d_in[2];
    const int*   sfaces = (const int*)d_in[3];
    const float* fp     = (const float*)d_in[4];
    const float* u1     = (const float*)d_in[5];
    const float* u2     = (const float*)d_in[6];
    float* out = (float*)d_out;

    const int N_ORIG = in_sizes[0] / 3;
    const int F_ORIG = in_sizes[1] / 3;
    const int F_SIMP = in_sizes[3] / 3;
    const int S      = in_sizes[5] / F_SIMP;
    const int NPTS   = F_SIMP * S;
    const int NQ     = NPTS + F_SIMP;

    // workspace: float4 arrays first (alignment), then unsigned arrays, then acc
    float4* sortedV = (float4*)d_ws;                       // N_ORIG
    float4* sortedB = sortedV + N_ORIG;                    // F_ORIG
    float4* obc4    = sortedB + F_ORIG;                    // F_ORIG
    unsigned* countsV = (unsigned*)(obc4 + F_ORIG);        // NV3
    unsigned* startsV = countsV + NV3;                     // NV3
    unsigned* cursorV = startsV + NV3;                     // NV3
    unsigned* countsB = cursorV + NV3;                     // NB3
    unsigned* startsB = countsB + NB3;                     // NB3
    unsigned* cursorB = startsB + NB3;                     // NB3
    float* acc = (float*)(cursorB + NB3);                  // 8

    int zeroN = max(NV3, NB3);
    hipLaunchKernelGGL(zero_kernel, dim3((zeroN + 255) / 256), dim3(256), 0, stream,
                       countsV, countsB, acc);

    int cntN = max(N_ORIG, F_ORIG);
    hipLaunchKernelGGL(count_kernel, dim3((cntN + 255) / 256), dim3(256), 0, stream,
                       overts, ofaces, obc4, countsV, countsB, N_ORIG, F_ORIG);

    hipLaunchKernelGGL(scan_kernel, dim3(2), dim3(1024), 0, stream,
                       countsV, startsV, cursorV, countsB, startsB, cursorB);

    hipLaunchKernelGGL(scatter_kernel, dim3((cntN + 255) / 256), dim3(256), 0, stream,
                       overts, obc4, cursorV, cursorB, sortedV, sortedB, N_ORIG, F_ORIG);

    const int qblocks = (NQ + QBLK - 1) / QBLK;
    hipLaunchKernelGGL(query_kernel, dim3(qblocks), dim3(QBLK), 0, stream,
                       sverts, sfaces, u1, u2, fp,
                       sortedV, startsV, countsV,
                       sortedB, startsB, countsB,
                       acc, out, F_SIMP, S, NPTS, NQ, qblocks);
}

// Round 15
// 165.871 us; speedup vs baseline: 2.8689x; 2.8689x over previous
//
#include <hip/hip_runtime.h>

#define EPSF 1e-8f
#define PROB_PENALTYF 1e-4f
#define REV_SCALEF 0.1f
#define INFBITS 0x7F800000u

// verts grid (rev sources: 8000 ~N(0,1) pts): 32^3, h=0.35, span +-5.6
#define NV 32
#define HV 0.35f
#define LOV (-5.6f)
#define NV3 (NV*NV*NV)          // 32768
// barycenter grid (fwd sources: 16000 bc, sigma~0.577): 32^3, h=0.21875, +-3.5
#define NB 32
#define HB 0.21875f
#define LOB (-3.5f)
#define NB3 (NB*NB*NB)          // 32768
#define NC (NV3 + NB3)          // 65536 cells total (B offset by NV3)

#define QBLK 128

__device__ __forceinline__ float min3f(float a, float b, float c) {
    return fminf(fminf(a, b), c);
}
__device__ __forceinline__ int cellc(float x, float lo, float invh, int n) {
    int c = (int)floorf((x - lo) * invh);
    return min(max(c, 0), n - 1);
}

// ---------------- kernel 0: zero counts + acc (incl. gcur=acc[4], ticket=acc[3]) ----------------
__global__ void zero_kernel(unsigned* __restrict__ counts, float* __restrict__ acc) {
    int i = blockIdx.x * blockDim.x + threadIdx.x;
    if (i < NC) counts[i] = 0u;
    if (i < 8)  acc[i] = 0.0f;
}

// ---------------- kernel 1: count (+ materialize orig barycenters) ----------------
__global__ void count_kernel(const float* __restrict__ overts,
                             const int* __restrict__ ofaces,
                             float4* __restrict__ obc4,
                             unsigned* __restrict__ counts,
                             int n_orig, int f_orig) {
    int i = blockIdx.x * blockDim.x + threadIdx.x;
    const float third = 1.0f / 3.0f;
    if (i < n_orig) {
        float x = overts[3*i], y = overts[3*i+1], z = overts[3*i+2];
        int cx = cellc(x, LOV, 1.0f/HV, NV);
        int cy = cellc(y, LOV, 1.0f/HV, NV);
        int cz = cellc(z, LOV, 1.0f/HV, NV);
        atomicAdd(&counts[(cz*NV + cy)*NV + cx], 1u);
    }
    if (i < f_orig) {
        int a = ofaces[3*i], b = ofaces[3*i+1], c = ofaces[3*i+2];
        float x = (overts[3*a] + overts[3*b] + overts[3*c]) * third;
        float y = (overts[3*a+1] + overts[3*b+1] + overts[3*c+1]) * third;
        float z = (overts[3*a+2] + overts[3*b+2] + overts[3*c+2]) * third;
        obc4[i] = make_float4(x, y, z, 0.f);
        int cx = cellc(x, LOB, 1.0f/HB, NB);
        int cy = cellc(y, LOB, 1.0f/HB, NB);
        int cz = cellc(z, LOB, 1.0f/HB, NB);
        atomicAdd(&counts[NV3 + (cz*NB + cy)*NB + cx], 1u);
    }
}

// ---------------- kernel 2: scan — 64 blocks x 1024 cells, atomic block base ----------------
// Block base via atomicAdd (order nondeterministic, but NN/min results are
// storage-order invariant => output deterministic). Within a block, starts are
// contiguous: starts[i+1] = starts[i]+counts[i]. Rows of 32 cells never straddle
// a 1024-cell block, so per-row ranges are contiguous (used by query kernel).
__global__ void __launch_bounds__(1024)
scan_kernel(const unsigned* __restrict__ counts,
            unsigned* __restrict__ starts,
            unsigned* __restrict__ cursor,
            unsigned* __restrict__ gcur) {
    __shared__ unsigned sh[1024];
    __shared__ unsigned sbase;
    int t = (int)threadIdx.x;
    int idx = blockIdx.x * 1024 + t;
    unsigned c = counts[idx];
    sh[t] = c;
    __syncthreads();
    for (int off = 1; off < 1024; off <<= 1) {
        unsigned v = sh[t];
        unsigned add = (t >= off) ? sh[t - off] : 0u;
        __syncthreads();
        sh[t] = v + add;
        __syncthreads();
    }
    unsigned incl = sh[t];
    if (t == 1023) sbase = atomicAdd(gcur, incl);
    __syncthreads();
    unsigned st = sbase + incl - c;
    starts[idx] = st;
    cursor[idx] = st;
}

// ---------------- kernel 3: scatter into sorted array ----------------
__global__ void scatter_kernel(const float* __restrict__ overts,
                               const float4* __restrict__ obc4,
                               unsigned* __restrict__ cursor,
                               float4* __restrict__ sorted,
                               int n_orig, int f_orig) {
    int i = blockIdx.x * blockDim.x + threadIdx.x;
    if (i < n_orig) {
        float x = overts[3*i], y = overts[3*i+1], z = overts[3*i+2];
        int cx = cellc(x, LOV, 1.0f/HV, NV);
        int cy = cellc(y, LOV, 1.0f/HV, NV);
        int cz = cellc(z, LOV, 1.0f/HV, NV);
        unsigned pos = atomicAdd(&cursor[(cz*NV + cy)*NV + cx], 1u);
        sorted[pos] = make_float4(x, y, z, 0.f);
    }
    if (i < f_orig) {
        float4 v = obc4[i];
        int cx = cellc(v.x, LOB, 1.0f/HB, NB);
        int cy = cellc(v.y, LOB, 1.0f/HB, NB);
        int cz = cellc(v.z, LOB, 1.0f/HB, NB);
        unsigned pos = atomicAdd(&cursor[NV3 + (cz*NB + cy)*NB + cx], 1u);
        sorted[pos] = make_float4(v.x, v.y, v.z, 0.f);
    }
}

// ---------------- kernel 4: grid 1-NN queries + fused reduction/finalize ----------------
// threads [0,npts): rev samples vs V grid; [npts,nq): fwd barycenters vs B grid.
// Cube phase: 9 contiguous row-ranges (27 batched meta loads), 4-wide unrolled
// point scan. Shell phase (rare): expanding Chebyshev shells, stop when
// best <= (r*h)^2 (bound valid under cell clamping, HW-verified in R13).
__global__ void __launch_bounds__(QBLK)
query_kernel(const float* __restrict__ sverts, const int* __restrict__ sfaces,
             const float* __restrict__ u1, const float* __restrict__ u2,
             const float* __restrict__ fp,
             const float4* __restrict__ sorted,
             const unsigned* __restrict__ starts,
             const unsigned* __restrict__ counts,
             float* __restrict__ acc, float* __restrict__ out,
             int fs, int S, int npts, int nq, int nblocks) {
    __shared__ float s1[QBLK], s2[QBLK], s3[QBLK];
    int t = blockIdx.x * blockDim.x + threadIdx.x;
    float fsum = 0.f, rsum = 0.f, rmx = 0.f;
    if (t < nq) {
        bool isRev = (t < npts);
        const float third = 1.0f / 3.0f;
        float qx, qy, qz;
        if (isRev) {
            int f = t / S;
            float rr = sqrtf(u1[t]);
            float uu = u2[t];
            float wa = 1.0f - rr, wb = rr * (1.0f - uu), wc = rr * uu;
            int a = sfaces[3*f], b = sfaces[3*f+1], c = sfaces[3*f+2];
            qx = wa * sverts[3*a] + wb * sverts[3*b] + wc * sverts[3*c];
            qy = wa * sverts[3*a+1] + wb * sverts[3*b+1] + wc * sverts[3*c+1];
            qz = wa * sverts[3*a+2] + wb * sverts[3*b+2] + wc * sverts[3*c+2];
        } else {
            int k = t - npts;
            int a = sfaces[3*k], b = sfaces[3*k+1], c = sfaces[3*k+2];
            qx = (sverts[3*a] + sverts[3*b] + sverts[3*c]) * third;
            qy = (sverts[3*a+1] + sverts[3*b+1] + sverts[3*c+1]) * third;
            qz = (sverts[3*a+2] + sverts[3*b+2] + sverts[3*c+2]) * third;
        }
        float lo = isRev ? LOV : LOB;
        float h  = isRev ? HV  : HB;
        int   n  = isRev ? NV  : NB;
        int   goff = isRev ? 0 : NV3;
        float invh = 1.0f / h;
        int cx = cellc(qx, lo, invh, n);
        int cy = cellc(qy, lo, invh, n);
        int cz = cellc(qz, lo, invh, n);
        float best = __uint_as_float(INFBITS);

        // ---- cube r<=1: 9 contiguous row-ranges, batched meta loads ----
        unsigned rs[9], re[9];
        int x0 = max(cx-1, 0), x1 = min(cx+1, n-1);
        #pragma unroll
        for (int dz = -1; dz <= 1; ++dz) {
            int z = min(max(cz + dz, 0), n-1);
            #pragma unroll
            for (int dy = -1; dy <= 1; ++dy) {
                int y = min(max(cy + dy, 0), n-1);
                int rowc = goff + (z*n + y)*n;
                int k = (dz+1)*3 + (dy+1);
                rs[k] = starts[rowc + x0];
                re[k] = starts[rowc + x1] + counts[rowc + x1];
            }
        }
        #pragma unroll
        for (int k = 0; k < 9; ++k) {
            unsigned i = rs[k], e = re[k];
            for (; i + 4 <= e; i += 4) {
                float4 v0 = sorted[i];
                float4 v1 = sorted[i+1];
                float4 v2 = sorted[i+2];
                float4 v3 = sorted[i+3];
                float dx0 = qx-v0.x, dy0 = qy-v0.y, dz0 = qz-v0.z;
                float dx1 = qx-v1.x, dy1 = qy-v1.y, dz1 = qz-v1.z;
                float dx2 = qx-v2.x, dy2 = qy-v2.y, dz2 = qz-v2.z;
                float dx3 = qx-v3.x, dy3 = qy-v3.y, dz3 = qz-v3.z;
                float d0 = fmaf(dx0,dx0, fmaf(dy0,dy0, dz0*dz0));
                float d1 = fmaf(dx1,dx1, fmaf(dy1,dy1, dz1*dz1));
                float d2 = fmaf(dx2,dx2, fmaf(dy2,dy2, dz2*dz2));
                float d3 = fmaf(dx3,dx3, fmaf(dy3,dy3, dz3*dz3));
                best = min3f(best, d0, d1);
                best = min3f(best, d2, d3);
            }
            for (; i < e; ++i) {
                float4 v = sorted[i];
                float dx = qx-v.x, dy = qy-v.y, dz = qz-v.z;
                best = fminf(best, fmaf(dx,dx, fmaf(dy,dy, dz*dz)));
            }
        }

        // ---- expanding shells (rare path; proven exact in R13) ----
        int rmaxq = max(max(cx, n-1-cx), max(max(cy, n-1-cy), max(cz, n-1-cz)));
        int r = 1;
        while (best > ((float)r * h) * ((float)r * h) && r < rmaxq) {
            ++r;
            for (int dz = -r; dz <= r; ++dz) {
                int z = cz + dz;
                if (z < 0 || z >= n) continue;
                bool zf = (dz == -r) || (dz == r);
                for (int dy = -r; dy <= r; ++dy) {
                    int y = cy + dy;
                    if (y < 0 || y >= n) continue;
                    bool yf = (dy == -r) || (dy == r);
                    int step = (zf || yf) ? 1 : 2 * r;
                    for (int dx = -r; dx <= r; dx += step) {
                        int x = cx + dx;
                        if (x < 0 || x >= n) continue;
                        int cid = goff + (z*n + y)*n + x;
                        unsigned sb = starts[cid];
                        unsigned e = sb + counts[cid];
                        for (unsigned i = sb; i < e; ++i) {
                            float4 v = sorted[i];
                            float ddx = qx-v.x, ddy = qy-v.y, ddz = qz-v.z;
                            best = fminf(best, fmaf(ddx,ddx, fmaf(ddy,ddy, ddz*ddz)));
                        }
                    }
                }
            }
        }

        if (isRev) {
            float p = fp[t / S];
            rsum = p * best;
            rmx = best;
        } else {
            float p = fp[t - npts];
            fsum = p * best + PROB_PENALTYF * (1.0f - p);
        }
    }

    // ---- block reduction + ticketed finalize ----
    s1[threadIdx.x] = fsum;
    s2[threadIdx.x] = rsum;
    s3[threadIdx.x] = rmx;
    __syncthreads();
    for (int off = QBLK / 2; off > 0; off >>= 1) {
        if ((int)threadIdx.x < off) {
            s1[threadIdx.x] += s1[threadIdx.x + off];
            s2[threadIdx.x] += s2[threadIdx.x + off];
            s3[threadIdx.x] = fmaxf(s3[threadIdx.x], s3[threadIdx.x + off]);
        }
        __syncthreads();
    }
    if (threadIdx.x == 0) {
        atomicAdd(&acc[0], s1[0]);
        atomicAdd(&acc[1], s2[0]);
        atomicMax((unsigned*)&acc[2], __float_as_uint(s3[0]));
        __threadfence();
        unsigned ticket = atomicAdd((unsigned*)&acc[3], 1u);
        if (ticket == (unsigned)(nblocks - 1)) {
            __threadfence();
            float a0 = atomicAdd(&acc[0], 0.0f);
            float a1 = atomicAdd(&acc[1], 0.0f);
            unsigned mb = atomicOr((unsigned*)&acc[2], 0u);
            out[0] = a0 + a1 * (REV_SCALEF / (__uint_as_float(mb) + EPSF));
        }
    }
}

extern "C" void kernel_launch(void* const* d_in, const int* in_sizes, int n_in,
                              void* d_out, int out_size, void* d_ws, size_t ws_size,
                              hipStream_t stream) {
    const float* overts = (const float*)d_in[0];
    const int*   ofaces = (const int*)d_in[1];
    const float* sverts = (const float*)d_in[2];
    const int*   sfaces = (const int*)d_in[3];
    const float* fp     = (const float*)d_in[4];
    const float* u1     = (const float*)d_in[5];
    const float* u2     = (const float*)d_in[6];
    float* out = (float*)d_out;

    const int N_ORIG = in_sizes[0] / 3;
    const int F_ORIG = in_sizes[1] / 3;
    const int F_SIMP = in_sizes[3] / 3;
    const int S      = in_sizes[5] / F_SIMP;
    const int NPTS   = F_SIMP * S;
    const int NQ     = NPTS + F_SIMP;

    // workspace: sorted[N_ORIG+F_ORIG] | obc4[F_ORIG] | counts | starts | cursor | acc(8f, gcur=acc[4])
    float4* sorted = (float4*)d_ws;
    float4* obc4   = sorted + (N_ORIG + F_ORIG);
    unsigned* counts = (unsigned*)(obc4 + F_ORIG);
    unsigned* starts = counts + NC;
    unsigned* cursor = starts + NC;
    float* acc = (float*)(cursor + NC);
    unsigned* gcur = (unsigned*)acc + 4;

    hipLaunchKernelGGL(zero_kernel, dim3(NC / 256), dim3(256), 0, stream, counts, acc);

    int cntN = max(N_ORIG, F_ORIG);
    hipLaunchKernelGGL(count_kernel, dim3((cntN + 255) / 256), dim3(256), 0, stream,
                       overts, ofaces, obc4, counts, N_ORIG, F_ORIG);

    hipLaunchKernelGGL(scan_kernel, dim3(NC / 1024), dim3(1024), 0, stream,
                       counts, starts, cursor, gcur);

    hipLaunchKernelGGL(scatter_kernel, dim3((cntN + 255) / 256), dim3(256), 0, stream,
                       overts, obc4, cursor, sorted, N_ORIG, F_ORIG);

    const int qblocks = (NQ + QBLK - 1) / QBLK;
    hipLaunchKernelGGL(query_kernel, dim3(qblocks), dim3(QBLK), 0, stream,
                       sverts, sfaces, u1, u2, fp,
                       sorted, starts, counts,
                       acc, out, F_SIMP, S, NPTS, NQ, qblocks);
}

// Round 16
// 147.609 us; speedup vs baseline: 3.2238x; 1.1237x over previous
//
#include <hip/hip_runtime.h>

#define EPSF 1e-8f
#define PROB_PENALTYF 1e-4f
#define REV_SCALEF 0.1f
#define INFBITS 0x7F800000u

// verts grid (rev sources: 8000 ~N(0,1) pts): 32^3, h=0.35, span +-5.6
#define NV 32
#define HV 0.35f
#define LOV (-5.6f)
#define NV3 (NV*NV*NV)          // 32768
// barycenter grid (fwd sources: 16000 bc, sigma~0.577): 32^3, h=0.21875, +-3.5
#define NB 32
#define HB 0.21875f
#define LOB (-3.5f)
#define NB3 (NB*NB*NB)          // 32768
#define NC (NV3 + NB3)          // 65536 cells total (B offset by NV3)

#define G 8                      // lanes per query (group within wave)
#define QBLK 256

__device__ __forceinline__ float min3f(float a, float b, float c) {
    return fminf(fminf(a, b), c);
}
__device__ __forceinline__ int cellc(float x, float lo, float invh, int n) {
    int c = (int)floorf((x - lo) * invh);
    return min(max(c, 0), n - 1);
}

// ---------------- kernel 0: zero counts + acc ----------------
__global__ void zero_kernel(unsigned* __restrict__ counts, float* __restrict__ acc) {
    int i = blockIdx.x * blockDim.x + threadIdx.x;
    if (i < NC) counts[i] = 0u;
    if (i < 8)  acc[i] = 0.0f;
}

// ---------------- kernel 1: count (+ materialize orig barycenters) ----------------
__global__ void count_kernel(const float* __restrict__ overts,
                             const int* __restrict__ ofaces,
                             float4* __restrict__ obc4,
                             unsigned* __restrict__ counts,
                             int n_orig, int f_orig) {
    int i = blockIdx.x * blockDim.x + threadIdx.x;
    const float third = 1.0f / 3.0f;
    if (i < n_orig) {
        float x = overts[3*i], y = overts[3*i+1], z = overts[3*i+2];
        int cx = cellc(x, LOV, 1.0f/HV, NV);
        int cy = cellc(y, LOV, 1.0f/HV, NV);
        int cz = cellc(z, LOV, 1.0f/HV, NV);
        atomicAdd(&counts[(cz*NV + cy)*NV + cx], 1u);
    }
    if (i < f_orig) {
        int a = ofaces[3*i], b = ofaces[3*i+1], c = ofaces[3*i+2];
        float x = (overts[3*a] + overts[3*b] + overts[3*c]) * third;
        float y = (overts[3*a+1] + overts[3*b+1] + overts[3*c+1]) * third;
        float z = (overts[3*a+2] + overts[3*b+2] + overts[3*c+2]) * third;
        obc4[i] = make_float4(x, y, z, 0.f);
        int cx = cellc(x, LOB, 1.0f/HB, NB);
        int cy = cellc(y, LOB, 1.0f/HB, NB);
        int cz = cellc(z, LOB, 1.0f/HB, NB);
        atomicAdd(&counts[NV3 + (cz*NB + cy)*NB + cx], 1u);
    }
}

// ---------------- kernel 2: scan — 64 blocks x 1024 cells, atomic block base ----------------
// Block bases via atomicAdd (nondeterministic order; NN/min results are
// storage-order invariant => output deterministic). Rows of 32 cells never
// straddle a block, so per-row start ranges are contiguous.
__global__ void __launch_bounds__(1024)
scan_kernel(const unsigned* __restrict__ counts,
            unsigned* __restrict__ starts,
            unsigned* __restrict__ cursor,
            unsigned* __restrict__ gcur) {
    __shared__ unsigned sh[1024];
    __shared__ unsigned sbase;
    int t = (int)threadIdx.x;
    int idx = blockIdx.x * 1024 + t;
    unsigned c = counts[idx];
    sh[t] = c;
    __syncthreads();
    for (int off = 1; off < 1024; off <<= 1) {
        unsigned v = sh[t];
        unsigned add = (t >= off) ? sh[t - off] : 0u;
        __syncthreads();
        sh[t] = v + add;
        __syncthreads();
    }
    unsigned incl = sh[t];
    if (t == 1023) sbase = atomicAdd(gcur, incl);
    __syncthreads();
    unsigned st = sbase + incl - c;
    starts[idx] = st;
    cursor[idx] = st;
}

// ---------------- kernel 3: scatter into sorted array ----------------
__global__ void scatter_kernel(const float* __restrict__ overts,
                               const float4* __restrict__ obc4,
                               unsigned* __restrict__ cursor,
                               float4* __restrict__ sorted,
                               int n_orig, int f_orig) {
    int i = blockIdx.x * blockDim.x + threadIdx.x;
    if (i < n_orig) {
        float x = overts[3*i], y = overts[3*i+1], z = overts[3*i+2];
        int cx = cellc(x, LOV, 1.0f/HV, NV);
        int cy = cellc(y, LOV, 1.0f/HV, NV);
        int cz = cellc(z, LOV, 1.0f/HV, NV);
        unsigned pos = atomicAdd(&cursor[(cz*NV + cy)*NV + cx], 1u);
        sorted[pos] = make_float4(x, y, z, 0.f);
    }
    if (i < f_orig) {
        float4 v = obc4[i];
        int cx = cellc(v.x, LOB, 1.0f/HB, NB);
        int cy = cellc(v.y, LOB, 1.0f/HB, NB);
        int cz = cellc(v.z, LOB, 1.0f/HB, NB);
        unsigned pos = atomicAdd(&cursor[NV3 + (cz*NB + cy)*NB + cx], 1u);
        sorted[pos] = make_float4(v.x, v.y, v.z, 0.f);
    }
}

// ---------------- kernel 4: cooperative grid 1-NN (8 lanes/query) + reduction ----------------
// Query q = tid/G, lane-in-group lg = tid%G (groups are lane-aligned in wave).
// Cube phase: 9 neighbor rows distributed lg -> rows {lg, lg+8}; per-lane 4-wide
// scan; 3-step shfl_xor group min. Shell phase (rare, proven exact R13):
// group-strided points per cell, group re-reduce per shell; stop when
// best <= (r*h)^2 (valid under cell clamping).
__global__ void __launch_bounds__(QBLK)
query_kernel(const float* __restrict__ sverts, const int* __restrict__ sfaces,
             const float* __restrict__ u1, const float* __restrict__ u2,
             const float* __restrict__ fp,
             const float4* __restrict__ sorted,
             const unsigned* __restrict__ starts,
             const unsigned* __restrict__ counts,
             float* __restrict__ acc, float* __restrict__ out,
             int fs, int S, int npts, int nq, int nblocks) {
    __shared__ float s1[QBLK], s2[QBLK], s3[QBLK];
    int tid = blockIdx.x * blockDim.x + threadIdx.x;
    int q = tid / G;
    int lg = tid & (G - 1);
    float fsum = 0.f, rsum = 0.f, rmx = 0.f;
    if (q < nq) {
        bool isRev = (q < npts);
        const float third = 1.0f / 3.0f;
        float qx, qy, qz;
        if (isRev) {
            int f = q / S;
            float rr = sqrtf(u1[q]);
            float uu = u2[q];
            float wa = 1.0f - rr, wb = rr * (1.0f - uu), wc = rr * uu;
            int a = sfaces[3*f], b = sfaces[3*f+1], c = sfaces[3*f+2];
            qx = wa * sverts[3*a] + wb * sverts[3*b] + wc * sverts[3*c];
            qy = wa * sverts[3*a+1] + wb * sverts[3*b+1] + wc * sverts[3*c+1];
            qz = wa * sverts[3*a+2] + wb * sverts[3*b+2] + wc * sverts[3*c+2];
        } else {
            int k = q - npts;
            int a = sfaces[3*k], b = sfaces[3*k+1], c = sfaces[3*k+2];
            qx = (sverts[3*a] + sverts[3*b] + sverts[3*c]) * third;
            qy = (sverts[3*a+1] + sverts[3*b+1] + sverts[3*c+1]) * third;
            qz = (sverts[3*a+2] + sverts[3*b+2] + sverts[3*c+2]) * third;
        }
        float lo = isRev ? LOV : LOB;
        float h  = isRev ? HV  : HB;
        int   n  = isRev ? NV  : NB;
        int   goff = isRev ? 0 : NV3;
        float invh = 1.0f / h;
        int cx = cellc(qx, lo, invh, n);
        int cy = cellc(qy, lo, invh, n);
        int cz = cellc(qz, lo, invh, n);
        float best = __uint_as_float(INFBITS);

        // ---- cube r<=1: rows lg and lg+8 of the 9 neighbor rows ----
        int x0 = max(cx-1, 0), x1 = min(cx+1, n-1);
        #pragma unroll
        for (int kk = 0; kk < 2; ++kk) {
            int k = lg + kk * 8;
            if (k < 9) {
                int z = min(max(cz + (k / 3) - 1, 0), n-1);
                int y = min(max(cy + (k % 3) - 1, 0), n-1);
                int rowc = goff + (z*n + y)*n;
                unsigned i = starts[rowc + x0];
                unsigned e = starts[rowc + x1] + counts[rowc + x1];
                for (; i + 4 <= e; i += 4) {
                    float4 v0 = sorted[i];
                    float4 v1 = sorted[i+1];
                    float4 v2 = sorted[i+2];
                    float4 v3 = sorted[i+3];
                    float dx0 = qx-v0.x, dy0 = qy-v0.y, dz0 = qz-v0.z;
                    float dx1 = qx-v1.x, dy1 = qy-v1.y, dz1 = qz-v1.z;
                    float dx2 = qx-v2.x, dy2 = qy-v2.y, dz2 = qz-v2.z;
                    float dx3 = qx-v3.x, dy3 = qy-v3.y, dz3 = qz-v3.z;
                    float d0 = fmaf(dx0,dx0, fmaf(dy0,dy0, dz0*dz0));
                    float d1 = fmaf(dx1,dx1, fmaf(dy1,dy1, dz1*dz1));
                    float d2 = fmaf(dx2,dx2, fmaf(dy2,dy2, dz2*dz2));
                    float d3 = fmaf(dx3,dx3, fmaf(dy3,dy3, dz3*dz3));
                    best = min3f(best, d0, d1);
                    best = min3f(best, d2, d3);
                }
                for (; i < e; ++i) {
                    float4 v = sorted[i];
                    float dx = qx-v.x, dy = qy-v.y, dz = qz-v.z;
                    best = fminf(best, fmaf(dx,dx, fmaf(dy,dy, dz*dz)));
                }
            }
        }
        // group min (groups are lane-aligned: xor 1,2,4 stays in-group)
        best = fminf(best, __shfl_xor(best, 1));
        best = fminf(best, __shfl_xor(best, 2));
        best = fminf(best, __shfl_xor(best, 4));

        // ---- expanding shells (rare; group-strided, re-reduced per shell) ----
        int rmaxq = max(max(cx, n-1-cx), max(max(cy, n-1-cy), max(cz, n-1-cz)));
        int r = 1;
        while (best > ((float)r * h) * ((float)r * h) && r < rmaxq) {
            ++r;
            for (int dz = -r; dz <= r; ++dz) {
                int z = cz + dz;
                if (z < 0 || z >= n) continue;
                bool zf = (dz == -r) || (dz == r);
                for (int dy = -r; dy <= r; ++dy) {
                    int y = cy + dy;
                    if (y < 0 || y >= n) continue;
                    bool yf = (dy == -r) || (dy == r);
                    int step = (zf || yf) ? 1 : 2 * r;
                    for (int dx = -r; dx <= r; dx += step) {
                        int x = cx + dx;
                        if (x < 0 || x >= n) continue;
                        int cid = goff + (z*n + y)*n + x;
                        unsigned sb = starts[cid];
                        unsigned e = sb + counts[cid];
                        for (unsigned i = sb + lg; i < e; i += G) {
                            float4 v = sorted[i];
                            float ddx = qx-v.x, ddy = qy-v.y, ddz = qz-v.z;
                            best = fminf(best, fmaf(ddx,ddx, fmaf(ddy,ddy, ddz*ddz)));
                        }
                    }
                }
            }
            best = fminf(best, __shfl_xor(best, 1));
            best = fminf(best, __shfl_xor(best, 2));
            best = fminf(best, __shfl_xor(best, 4));
        }

        if (lg == 0) {
            if (isRev) {
                float p = fp[q / S];
                rsum = p * best;
                rmx = best;
            } else {
                float p = fp[q - npts];
                fsum = p * best + PROB_PENALTYF * (1.0f - p);
            }
        }
    }

    // ---- block reduction + ticketed finalize ----
    s1[threadIdx.x] = fsum;
    s2[threadIdx.x] = rsum;
    s3[threadIdx.x] = rmx;
    __syncthreads();
    for (int off = QBLK / 2; off > 0; off >>= 1) {
        if ((int)threadIdx.x < off) {
            s1[threadIdx.x] += s1[threadIdx.x + off];
            s2[threadIdx.x] += s2[threadIdx.x + off];
            s3[threadIdx.x] = fmaxf(s3[threadIdx.x], s3[threadIdx.x + off]);
        }
        __syncthreads();
    }
    if (threadIdx.x == 0) {
        atomicAdd(&acc[0], s1[0]);
        atomicAdd(&acc[1], s2[0]);
        atomicMax((unsigned*)&acc[2], __float_as_uint(s3[0]));
        __threadfence();
        unsigned ticket = atomicAdd((unsigned*)&acc[3], 1u);
        if (ticket == (unsigned)(nblocks - 1)) {
            __threadfence();
            float a0 = atomicAdd(&acc[0], 0.0f);
            float a1 = atomicAdd(&acc[1], 0.0f);
            unsigned mb = atomicOr((unsigned*)&acc[2], 0u);
            out[0] = a0 + a1 * (REV_SCALEF / (__uint_as_float(mb) + EPSF));
        }
    }
}

extern "C" void kernel_launch(void* const* d_in, const int* in_sizes, int n_in,
                              void* d_out, int out_size, void* d_ws, size_t ws_size,
                              hipStream_t stream) {
    const float* overts = (const float*)d_in[0];
    const int*   ofaces = (const int*)d_in[1];
    const float* sverts = (const float*)d_in[2];
    const int*   sfaces = (const int*)d_in[3];
    const float* fp     = (const float*)d_in[4];
    const float* u1     = (const float*)d_in[5];
    const float* u2     = (const float*)d_in[6];
    float* out = (float*)d_out;

    const int N_ORIG = in_sizes[0] / 3;
    const int F_ORIG = in_sizes[1] / 3;
    const int F_SIMP = in_sizes[3] / 3;
    const int S      = in_sizes[5] / F_SIMP;
    const int NPTS   = F_SIMP * S;
    const int NQ     = NPTS + F_SIMP;

    // workspace: sorted[N_ORIG+F_ORIG] | obc4[F_ORIG] | counts | starts | cursor | acc(8f, gcur=acc[4])
    float4* sorted = (float4*)d_ws;
    float4* obc4   = sorted + (N_ORIG + F_ORIG);
    unsigned* counts = (unsigned*)(obc4 + F_ORIG);
    unsigned* starts = counts + NC;
    unsigned* cursor = starts + NC;
    float* acc = (float*)(cursor + NC);
    unsigned* gcur = (unsigned*)acc + 4;

    hipLaunchKernelGGL(zero_kernel, dim3(NC / 256), dim3(256), 0, stream, counts, acc);

    int cntN = max(N_ORIG, F_ORIG);
    hipLaunchKernelGGL(count_kernel, dim3((cntN + 255) / 256), dim3(256), 0, stream,
                       overts, ofaces, obc4, counts, N_ORIG, F_ORIG);

    hipLaunchKernelGGL(scan_kernel, dim3(NC / 1024), dim3(1024), 0, stream,
                       counts, starts, cursor, gcur);

    hipLaunchKernelGGL(scatter_kernel, dim3((cntN + 255) / 256), dim3(256), 0, stream,
                       overts, obc4, cursor, sorted, N_ORIG, F_ORIG);

    const int qblocks = (NQ * G + QBLK - 1) / QBLK;
    hipLaunchKernelGGL(query_kernel, dim3(qblocks), dim3(QBLK), 0, stream,
                       sverts, sfaces, u1, u2, fp,
                       sorted, starts, counts,
                       acc, out, F_SIMP, S, NPTS, NQ, qblocks);
}